// Round 10
// baseline (102.503 us; speedup 1.0000x reference)
//
#include <hip/hip_runtime.h>

#define NCLS   80
#define NB     8
#define NGT    32
#define NANCH  36864                 // anchors per image (9*64*64)
#define APB    128                   // anchors per block
#define NTHR   256
#define NBLK   2304                  // 8*36864/128
#define BLKS_PER_IMG 288
#define KI     10                    // float4 per thread (128*20/256), no remainder

#define LOG2E 1.4426950408889634f
#define LN2   0.6931471805599453f

// Anchor W/H computed in double (matches Python float arithmetic), cast to f32.
__device__ __constant__ float c_aw[9] = {
    (float)(32.0 * 1.0    * 1.0), (float)(32.0 * 1.0    * 1.4), (float)(32.0 * 1.0    * 0.7),
    (float)(32.0 * 1.2599 * 1.0), (float)(32.0 * 1.2599 * 1.4), (float)(32.0 * 1.2599 * 0.7),
    (float)(32.0 * 1.5874 * 1.0), (float)(32.0 * 1.5874 * 1.4), (float)(32.0 * 1.5874 * 0.7)};
__device__ __constant__ float c_ah[9] = {
    (float)(32.0 * 1.0    * 1.0), (float)(32.0 * 1.0    * 0.7), (float)(32.0 * 1.0    * 1.4),
    (float)(32.0 * 1.2599 * 1.0), (float)(32.0 * 1.2599 * 0.7), (float)(32.0 * 1.2599 * 1.4),
    (float)(32.0 * 1.5874 * 1.0), (float)(32.0 * 1.5874 * 0.7), (float)(32.0 * 1.5874 * 1.4)};

// part[blk] = {sum_log2_terms, xywh_loss, pos_count, hot_sum}
__global__ __launch_bounds__(NTHR, 8) void retina_main(
    const float* __restrict__ t_xywh,      // [B, N, 4]
    const float* __restrict__ cls_logits,  // [B, N, 80]
    const float* __restrict__ gt_bboxes,   // [B, 32, 4] cxcywh
    const int*   __restrict__ gt_cats,     // [B, 32]
    float4* __restrict__ part,             // [NBLK]
    unsigned int* __restrict__ counter,    // zeroed per launch
    float* __restrict__ out)
{
    __shared__ float4 s_gtl[NGT];      // {tlx, tly, brx, bry}
    __shared__ float  s_ga[NGT];       // area_g
    __shared__ int    s_cat[NGT];
    __shared__ float  s_best[NTHR];
    __shared__ int    s_bi[NTHR];
    __shared__ float  s_mask[APB];     // 1.0 if penalty anchor else 0.0
    __shared__ float  s_red[4 * 4];
    __shared__ int    s_last;

    const int tid = threadIdx.x;
    const int blk = blockIdx.x;
    const int b   = blk / BLKS_PER_IMG;
    const int la0 = tid & (APB - 1);       // anchor owned for IoU
    const int gh  = tid >> 7;              // GT half: 0 -> 0..15, 1 -> 16..31

    const float4* gt4  = (const float4*)gt_bboxes + b * NGT;
    const int*    gcat = gt_cats + b * NGT;

    // ---- stage precomputed GT geometry (bit-exact ops vs numpy) ----
    {
#pragma clang fp contract(off)
        if (tid < NGT) {
            const float4 gb = gt4[tid];
            s_gtl[tid] = make_float4(gb.x - gb.z * 0.5f, gb.y - gb.w * 0.5f,
                                     gb.x + gb.z * 0.5f, gb.y + gb.w * 0.5f);
            s_ga[tid]  = gb.z * gb.w;
            s_cat[tid] = gcat[tid];
        }
    }
    __syncthreads();

    // ---- anchor geometry ----
    const int n  = (blk % BLKS_PER_IMG) * APB + la0;   // anchor within image
    const int a  = n >> 12;
    const int hy = (n >> 6) & 63;
    const int wx = n & 63;
    const float acx = (wx + 0.5f) * 8.0f;
    const float acy = (hy + 0.5f) * 8.0f;
    const float aw  = c_aw[a];
    const float ah  = c_ah[a];

    // ---- IoU vs 16 GTs per thread (halves split across thread halves) ----
    float best = -1.0f;
    int   bi   = 0;
    {
#pragma clang fp contract(off)
        const float a_tlx = acx - aw * 0.5f, a_tly = acy - ah * 0.5f;
        const float a_brx = acx + aw * 0.5f, a_bry = acy + ah * 0.5f;
        const float area_a = aw * ah;
        const int g0 = gh * 16;
        for (int j = 0; j < 16; ++j) {
            const int gg = g0 + j;
            const float4 e4 = s_gtl[gg];        // wave-uniform -> LDS broadcast
            float dx = fminf(a_brx, e4.z) - fmaxf(a_tlx, e4.x);
            float dy = fminf(a_bry, e4.w) - fmaxf(a_tly, e4.y);
            dx = fmaxf(dx, 0.0f);
            dy = fmaxf(dy, 0.0f);
            const float inter = dx * dy;
            const float uni   = (area_a + s_ga[gg]) - inter;
            const float iou   = inter * __builtin_amdgcn_rcpf(uni);
            if (iou > best) { best = iou; bi = gg; }   // strict > = first argmax
        }
    }
    s_best[tid] = best;
    s_bi[tid]   = bi;
    __syncthreads();

    // ---- combine halves, flags->mask, xywh loss + hot gather (rare lanes) ----
    float lx = 0.0f, pcnt = 0.0f, hot = 0.0f;
    if (tid < APB) {
        const float bhi = s_best[tid + APB];
        if (bhi > best) { best = bhi; bi = s_bi[tid + APB]; }
        const bool pos = best > 0.5f;
        const bool neg = best < 0.4f;
        if (pos) {                                 // rare (~0.4% of anchors)
            const int cat = s_cat[bi];
            pcnt = 1.0f;
            hot  = cls_logits[((size_t)blk * APB + tid) * NCLS + cat];
            const float4 g = gt4[bi];
            const float4 t = ((const float4*)t_xywh)[(size_t)b * NANCH + n];
            const float tx = (g.x - acx) / aw;
            const float ty = (g.y - acy) / ah;
            const float tw = logf(g.z / aw + 1e-8f);
            const float th = logf(g.w / ah + 1e-8f);
            const float d0 = t.x - tx, d1 = t.y - ty, d2 = t.z - tw, d3 = t.w - th;
            lx = d0 * d0 + d1 * d1 + d2 * d2 + d3 * d3;
        }
        s_mask[tid] = (pos | neg) ? 1.0f : 0.0f;
    }
    __syncthreads();   // streaming loads start AFTER this barrier

    // ---- streaming BCE: softplus(x) = ln2 * log2(1 + 2^(x*log2e)) ----
    const float4* base = (const float4*)cls_logits + (size_t)blk * (APB * NCLS / 4);
    float l2 = 0.0f;
#pragma unroll
    for (int k = 0; k < KI; ++k) {
        const int e  = k * NTHR + tid;       // f4 index within block slice
        const int la = e / 20;               // owning anchor (20 f4 per anchor)
        const float4 x = base[e];
        const float m  = s_mask[la];
        const float t0 = __builtin_amdgcn_exp2f(x.x * LOG2E);
        const float t1 = __builtin_amdgcn_exp2f(x.y * LOG2E);
        const float t2 = __builtin_amdgcn_exp2f(x.z * LOG2E);
        const float t3 = __builtin_amdgcn_exp2f(x.w * LOG2E);
        const float g0 = __builtin_amdgcn_logf(1.0f + t0);
        const float g1 = __builtin_amdgcn_logf(1.0f + t1);
        const float g2 = __builtin_amdgcn_logf(1.0f + t2);
        const float g3 = __builtin_amdgcn_logf(1.0f + t3);
        l2 += m * ((g0 + g1) + (g2 + g3));
    }

    // ---- block reduction of (l2, lx, pcnt, hot) ----
    float v0 = l2, v1 = lx, v2 = pcnt, v3 = hot;
    for (int o = 32; o > 0; o >>= 1) {
        v0 += __shfl_down(v0, o);
        v1 += __shfl_down(v1, o);
        v2 += __shfl_down(v2, o);
        v3 += __shfl_down(v3, o);
    }
    const int wave = tid >> 6;
    if ((tid & 63) == 0) {
        s_red[wave * 4 + 0] = v0;
        s_red[wave * 4 + 1] = v1;
        s_red[wave * 4 + 2] = v2;
        s_red[wave * 4 + 3] = v3;
    }
    __syncthreads();
    if (tid == 0) {
        float q0 = 0.0f, q1 = 0.0f, q2 = 0.0f, q3 = 0.0f;
        for (int w2 = 0; w2 < 4; ++w2) {
            q0 += s_red[w2 * 4 + 0];
            q1 += s_red[w2 * 4 + 1];
            q2 += s_red[w2 * 4 + 2];
            q3 += s_red[w2 * 4 + 3];
        }
        part[blk] = make_float4(q0, q1, q2, q3);
        __threadfence();                       // release partials device-wide
        const unsigned old = atomicAdd(counter, 1u);
        s_last = (old == NBLK - 1) ? 1 : 0;
    }
    __syncthreads();

    // ---- last block folds all 2304 partials into the scalar loss ----
    if (s_last) {
        __threadfence();                       // acquire
        __shared__ float s_l2[NB], s_pc[NB], s_ht[NB], s_lxr[NB];
        const int img = tid >> 5, l = tid & 31;    // 32 lanes per image
        float l2s = 0.0f, lxs = 0.0f, pcs = 0.0f, hts = 0.0f;
        for (int i = l; i < BLKS_PER_IMG; i += 32) {
            const float4 p = part[img * BLKS_PER_IMG + i];
            l2s += p.x; lxs += p.y; pcs += p.z; hts += p.w;
        }
        for (int o = 16; o > 0; o >>= 1) {     // xor butterfly within the 32-group
            l2s += __shfl_xor(l2s, o);
            lxs += __shfl_xor(lxs, o);
            pcs += __shfl_xor(pcs, o);
            hts += __shfl_xor(hts, o);
        }
        if (l == 0) { s_l2[img] = l2s; s_pc[img] = pcs; s_ht[img] = hts; s_lxr[img] = lxs; }
        __syncthreads();
        if (tid == 0) {
            float s = 0.0f, lxt = 0.0f;
            for (int bb = 0; bb < NB; ++bb) {
                lxt += s_lxr[bb];
                const float lc_b = LN2 * s_l2[bb] - s_ht[bb];
                s += lc_b / (s_pc[bb] + 1.0f);
            }
            out[0] = (lxt + s) / (float)NB;
        }
    }
}

extern "C" void kernel_launch(void* const* d_in, const int* in_sizes, int n_in,
                              void* d_out, int out_size, void* d_ws, size_t ws_size,
                              hipStream_t stream)
{
    const float* t_xywh     = (const float*)d_in[0];
    const float* cls_logits = (const float*)d_in[1];
    const float* gt_bboxes  = (const float*)d_in[2];
    const int*   gt_cats    = (const int*)d_in[3];

    float4* part = (float4*)d_ws;                                  // 2304 * 16 B
    unsigned int* counter = (unsigned int*)((char*)d_ws + NBLK * sizeof(float4));

    hipMemsetAsync(counter, 0, sizeof(unsigned int), stream);
    retina_main<<<NBLK, NTHR, 0, stream>>>(t_xywh, cls_logits, gt_bboxes, gt_cats,
                                           part, counter, (float*)d_out);
}

// Round 11
// 26.850 us; speedup vs baseline: 3.8176x; 3.8176x over previous
//
#include <hip/hip_runtime.h>

#define NCLS   80
#define NB     8
#define NGT    32
#define NANCH  36864                 // anchors per image (9*64*64)
#define APB    128                   // anchors per block
#define NTHR   256
#define NBLK   2304                  // 8*36864/128
#define BLKS_PER_IMG 288
#define KI     10                    // float4 per thread (128*20/256), no remainder

#define LOG2E 1.4426950408889634f
#define LN2   0.6931471805599453f

// Anchor W/H computed in double (matches Python float arithmetic), cast to f32.
__device__ __constant__ float c_aw[9] = {
    (float)(32.0 * 1.0    * 1.0), (float)(32.0 * 1.0    * 1.4), (float)(32.0 * 1.0    * 0.7),
    (float)(32.0 * 1.2599 * 1.0), (float)(32.0 * 1.2599 * 1.4), (float)(32.0 * 1.2599 * 0.7),
    (float)(32.0 * 1.5874 * 1.0), (float)(32.0 * 1.5874 * 1.4), (float)(32.0 * 1.5874 * 0.7)};
__device__ __constant__ float c_ah[9] = {
    (float)(32.0 * 1.0    * 1.0), (float)(32.0 * 1.0    * 0.7), (float)(32.0 * 1.0    * 1.4),
    (float)(32.0 * 1.2599 * 1.0), (float)(32.0 * 1.2599 * 0.7), (float)(32.0 * 1.2599 * 1.4),
    (float)(32.0 * 1.5874 * 1.0), (float)(32.0 * 1.5874 * 0.7), (float)(32.0 * 1.5874 * 1.4)};

// part[blk] = {sum_log2_terms, xywh_loss, pos_count, hot_sum}
__global__ __launch_bounds__(NTHR, 8) void retina_main(
    const float* __restrict__ t_xywh,      // [B, N, 4]
    const float* __restrict__ cls_logits,  // [B, N, 80]
    const float* __restrict__ gt_bboxes,   // [B, 32, 4] cxcywh
    const int*   __restrict__ gt_cats,     // [B, 32]
    float4* __restrict__ part)             // [NBLK]
{
    __shared__ float4 s_gtl[NGT];      // {tlx, tly, brx, bry}
    __shared__ float  s_ga[NGT];       // area_g
    __shared__ int    s_cat[NGT];
    __shared__ float  s_best[NTHR];
    __shared__ int    s_bi[NTHR];
    __shared__ float  s_mask[APB];     // 1.0 if penalty anchor else 0.0
    __shared__ float  s_red[4 * 4];

    const int tid = threadIdx.x;
    const int blk = blockIdx.x;
    const int b   = blk / BLKS_PER_IMG;
    const int la0 = tid & (APB - 1);       // anchor owned for IoU
    const int gh  = tid >> 7;              // GT half: 0 -> 0..15, 1 -> 16..31

    const float4* gt4  = (const float4*)gt_bboxes + b * NGT;
    const int*    gcat = gt_cats + b * NGT;

    // ---- stage precomputed GT geometry (bit-exact ops vs numpy) ----
    {
#pragma clang fp contract(off)
        if (tid < NGT) {
            const float4 gb = gt4[tid];
            s_gtl[tid] = make_float4(gb.x - gb.z * 0.5f, gb.y - gb.w * 0.5f,
                                     gb.x + gb.z * 0.5f, gb.y + gb.w * 0.5f);
            s_ga[tid]  = gb.z * gb.w;
            s_cat[tid] = gcat[tid];
        }
    }
    __syncthreads();

    // ---- anchor geometry ----
    const int n  = (blk % BLKS_PER_IMG) * APB + la0;   // anchor within image
    const int a  = n >> 12;
    const int hy = (n >> 6) & 63;
    const int wx = n & 63;
    const float acx = (wx + 0.5f) * 8.0f;
    const float acy = (hy + 0.5f) * 8.0f;
    const float aw  = c_aw[a];
    const float ah  = c_ah[a];

    // ---- IoU vs 16 GTs per thread (halves split across thread halves) ----
    float best = -1.0f;
    int   bi   = 0;
    {
#pragma clang fp contract(off)
        const float a_tlx = acx - aw * 0.5f, a_tly = acy - ah * 0.5f;
        const float a_brx = acx + aw * 0.5f, a_bry = acy + ah * 0.5f;
        const float area_a = aw * ah;
        const int g0 = gh * 16;
        for (int j = 0; j < 16; ++j) {
            const int gg = g0 + j;
            const float4 e4 = s_gtl[gg];        // wave-uniform -> LDS broadcast
            float dx = fminf(a_brx, e4.z) - fmaxf(a_tlx, e4.x);
            float dy = fminf(a_bry, e4.w) - fmaxf(a_tly, e4.y);
            dx = fmaxf(dx, 0.0f);
            dy = fmaxf(dy, 0.0f);
            const float inter = dx * dy;
            const float uni   = (area_a + s_ga[gg]) - inter;
            const float iou   = inter * __builtin_amdgcn_rcpf(uni);
            if (iou > best) { best = iou; bi = gg; }   // strict > = first argmax
        }
    }
    s_best[tid] = best;
    s_bi[tid]   = bi;
    __syncthreads();

    // ---- combine halves, flags->mask, xywh loss + hot gather (rare lanes) ----
    float lx = 0.0f, pcnt = 0.0f, hot = 0.0f;
    if (tid < APB) {
        const float bhi = s_best[tid + APB];
        if (bhi > best) { best = bhi; bi = s_bi[tid + APB]; }
        const bool pos = best > 0.5f;
        const bool neg = best < 0.4f;
        if (pos) {                                 // rare (~0.4% of anchors)
            const int cat = s_cat[bi];
            pcnt = 1.0f;
            hot  = cls_logits[((size_t)blk * APB + tid) * NCLS + cat];
            const float4 g = gt4[bi];
            const float4 t = ((const float4*)t_xywh)[(size_t)b * NANCH + n];
            const float tx = (g.x - acx) / aw;
            const float ty = (g.y - acy) / ah;
            const float tw = logf(g.z / aw + 1e-8f);
            const float th = logf(g.w / ah + 1e-8f);
            const float d0 = t.x - tx, d1 = t.y - ty, d2 = t.z - tw, d3 = t.w - th;
            lx = d0 * d0 + d1 * d1 + d2 * d2 + d3 * d3;
        }
        s_mask[tid] = (pos | neg) ? 1.0f : 0.0f;
    }
    __syncthreads();   // streaming loads start AFTER this barrier

    // ---- streaming BCE: softplus(x) = ln2 * log2(1 + 2^(x*log2e)) ----
    const float4* base = (const float4*)cls_logits + (size_t)blk * (APB * NCLS / 4);
    float l2 = 0.0f;
#pragma unroll
    for (int k = 0; k < KI; ++k) {
        const int e  = k * NTHR + tid;       // f4 index within block slice
        const int la = e / 20;               // owning anchor (20 f4 per anchor)
        const float4 x = base[e];
        const float m  = s_mask[la];
        const float t0 = __builtin_amdgcn_exp2f(x.x * LOG2E);
        const float t1 = __builtin_amdgcn_exp2f(x.y * LOG2E);
        const float t2 = __builtin_amdgcn_exp2f(x.z * LOG2E);
        const float t3 = __builtin_amdgcn_exp2f(x.w * LOG2E);
        const float g0 = __builtin_amdgcn_logf(1.0f + t0);
        const float g1 = __builtin_amdgcn_logf(1.0f + t1);
        const float g2 = __builtin_amdgcn_logf(1.0f + t2);
        const float g3 = __builtin_amdgcn_logf(1.0f + t3);
        l2 += m * ((g0 + g1) + (g2 + g3));
    }

    // ---- block reduction of (l2, lx, pcnt, hot) ----
    float v0 = l2, v1 = lx, v2 = pcnt, v3 = hot;
    for (int o = 32; o > 0; o >>= 1) {
        v0 += __shfl_down(v0, o);
        v1 += __shfl_down(v1, o);
        v2 += __shfl_down(v2, o);
        v3 += __shfl_down(v3, o);
    }
    const int wave = tid >> 6;
    if ((tid & 63) == 0) {
        s_red[wave * 4 + 0] = v0;
        s_red[wave * 4 + 1] = v1;
        s_red[wave * 4 + 2] = v2;
        s_red[wave * 4 + 3] = v3;
    }
    __syncthreads();
    if (tid == 0) {
        float q0 = 0.0f, q1 = 0.0f, q2 = 0.0f, q3 = 0.0f;
        for (int w2 = 0; w2 < 4; ++w2) {
            q0 += s_red[w2 * 4 + 0];
            q1 += s_red[w2 * 4 + 1];
            q2 += s_red[w2 * 4 + 2];
            q3 += s_red[w2 * 4 + 3];
        }
        part[blk] = make_float4(q0, q1, q2, q3);
    }
}

// ---- fold 2304 block partials into the scalar loss ----
__global__ __launch_bounds__(256) void retina_final(
    const float4* __restrict__ part, float* __restrict__ out)
{
    __shared__ float s_l2[NB], s_pc[NB], s_ht[NB], s_lxr[NB];
    const int tid = threadIdx.x;
    const int img = tid >> 5, l = tid & 31;    // 32 lanes per image

    float l2s = 0.0f, lxs = 0.0f, pcs = 0.0f, hts = 0.0f;
    for (int i = l; i < BLKS_PER_IMG; i += 32) {
        const float4 p = part[img * BLKS_PER_IMG + i];
        l2s += p.x; lxs += p.y; pcs += p.z; hts += p.w;
    }
    for (int o = 16; o > 0; o >>= 1) {         // xor butterfly within the 32-group
        l2s += __shfl_xor(l2s, o);
        lxs += __shfl_xor(lxs, o);
        pcs += __shfl_xor(pcs, o);
        hts += __shfl_xor(hts, o);
    }
    if (l == 0) { s_l2[img] = l2s; s_pc[img] = pcs; s_ht[img] = hts; s_lxr[img] = lxs; }
    __syncthreads();

    if (tid == 0) {
        float s = 0.0f, lxt = 0.0f;
        for (int bb = 0; bb < NB; ++bb) {
            lxt += s_lxr[bb];
            const float lc_b = LN2 * s_l2[bb] - s_ht[bb];
            s += lc_b / (s_pc[bb] + 1.0f);
        }
        out[0] = (lxt + s) / (float)NB;
    }
}

extern "C" void kernel_launch(void* const* d_in, const int* in_sizes, int n_in,
                              void* d_out, int out_size, void* d_ws, size_t ws_size,
                              hipStream_t stream)
{
    const float* t_xywh     = (const float*)d_in[0];
    const float* cls_logits = (const float*)d_in[1];
    const float* gt_bboxes  = (const float*)d_in[2];
    const int*   gt_cats    = (const int*)d_in[3];

    float4* part = (float4*)d_ws;   // 2304 * 16 B = 36.9 KB

    retina_main<<<NBLK, NTHR, 0, stream>>>(t_xywh, cls_logits, gt_bboxes, gt_cats, part);
    retina_final<<<1, 256, 0, stream>>>(part, (float*)d_out);
}

// Round 12
// 26.067 us; speedup vs baseline: 3.9322x; 1.0300x over previous
//
#include <hip/hip_runtime.h>

#define NCLS   80
#define NB     8
#define NGT    32
#define NANCH  36864                 // anchors per image (9*64*64)
#define APB    128                   // anchors per block
#define NTHR   256
#define NBLK   2304                  // 8*36864/128
#define BLKS_PER_IMG 288
#define KI     10                    // float4 per thread (128*20/256), no remainder

#define LOG2E 1.4426950408889634f
#define LN2   0.6931471805599453f

// Anchor W/H computed in double (matches Python float arithmetic), cast to f32.
__device__ __constant__ float c_aw[9] = {
    (float)(32.0 * 1.0    * 1.0), (float)(32.0 * 1.0    * 1.4), (float)(32.0 * 1.0    * 0.7),
    (float)(32.0 * 1.2599 * 1.0), (float)(32.0 * 1.2599 * 1.4), (float)(32.0 * 1.2599 * 0.7),
    (float)(32.0 * 1.5874 * 1.0), (float)(32.0 * 1.5874 * 1.4), (float)(32.0 * 1.5874 * 0.7)};
__device__ __constant__ float c_ah[9] = {
    (float)(32.0 * 1.0    * 1.0), (float)(32.0 * 1.0    * 0.7), (float)(32.0 * 1.0    * 1.4),
    (float)(32.0 * 1.2599 * 1.0), (float)(32.0 * 1.2599 * 0.7), (float)(32.0 * 1.2599 * 1.4),
    (float)(32.0 * 1.5874 * 1.0), (float)(32.0 * 1.5874 * 0.7), (float)(32.0 * 1.5874 * 1.4)};

// Softplus accumulate in log2 units for one register-resident float4.
#define COMP(X, K)                                                    \
    {                                                                 \
        const float m  = mk[K];                                       \
        const float t0 = __builtin_amdgcn_exp2f((X).x * LOG2E);       \
        const float t1 = __builtin_amdgcn_exp2f((X).y * LOG2E);       \
        const float t2 = __builtin_amdgcn_exp2f((X).z * LOG2E);       \
        const float t3 = __builtin_amdgcn_exp2f((X).w * LOG2E);       \
        const float g0 = __builtin_amdgcn_logf(1.0f + t0);            \
        const float g1 = __builtin_amdgcn_logf(1.0f + t1);            \
        const float g2 = __builtin_amdgcn_logf(1.0f + t2);            \
        const float g3 = __builtin_amdgcn_logf(1.0f + t3);            \
        l2 += m * ((g0 + g1) + (g2 + g3));                            \
    }

// part[blk] = {sum_log2_terms, xywh_loss, pos_count, hot_sum}
__global__ __launch_bounds__(NTHR, 8) void retina_main(
    const float* __restrict__ t_xywh,      // [B, N, 4]
    const float* __restrict__ cls_logits,  // [B, N, 80]
    const float* __restrict__ gt_bboxes,   // [B, 32, 4] cxcywh
    const int*   __restrict__ gt_cats,     // [B, 32]
    float4* __restrict__ part)             // [NBLK]
{
    __shared__ float s_best[NTHR];
    __shared__ int   s_bi[NTHR];
    __shared__ float s_mask[APB];     // 1.0 if penalty anchor else 0.0
    __shared__ float s_red[4 * 4];

    const int tid = threadIdx.x;
    const int blk = blockIdx.x;
    const int b   = blk / BLKS_PER_IMG;
    const int la0 = tid & (APB - 1);       // anchor owned for IoU
    const int gh  = tid >> 7;              // GT half: 0 -> 0..15, 1 -> 16..31

    const float4* base = (const float4*)cls_logits + (size_t)blk * (APB * NCLS / 4);

    // ---- prime 4 streaming loads; the IoU phase below hides their latency ----
    float4 P0 = base[0 * NTHR + tid];
    float4 P1 = base[1 * NTHR + tid];
    float4 P2 = base[2 * NTHR + tid];
    float4 P3 = base[3 * NTHR + tid];

    const float4* gt4  = (const float4*)gt_bboxes + b * NGT;
    const int*    gcat = gt_cats + b * NGT;

    // ---- anchor geometry ----
    const int n  = (blk % BLKS_PER_IMG) * APB + la0;   // anchor within image
    const int a  = n >> 12;
    const int hy = (n >> 6) & 63;
    const int wx = n & 63;
    const float acx = (wx + 0.5f) * 8.0f;
    const float acy = (hy + 0.5f) * 8.0f;
    const float aw  = c_aw[a];
    const float ah  = c_ah[a];

    // ---- IoU vs 16 GTs per thread (inline edges; overlaps the primed loads) ----
    float best = -1.0f;
    int   bi   = 0;
    {
#pragma clang fp contract(off)
        const float a_tlx = acx - aw * 0.5f, a_tly = acy - ah * 0.5f;
        const float a_brx = acx + aw * 0.5f, a_bry = acy + ah * 0.5f;
        const float area_a = aw * ah;
        const int g0 = gh * 16;
#pragma unroll
        for (int j = 0; j < 16; ++j) {
            const int gg = g0 + j;
            const float4 gb = gt4[gg];               // wave-uniform -> s_load
            const float g_tlx = gb.x - gb.z * 0.5f, g_tly = gb.y - gb.w * 0.5f;
            const float g_brx = gb.x + gb.z * 0.5f, g_bry = gb.y + gb.w * 0.5f;
            float dx = fminf(a_brx, g_brx) - fmaxf(a_tlx, g_tlx);
            float dy = fminf(a_bry, g_bry) - fmaxf(a_tly, g_tly);
            dx = fmaxf(dx, 0.0f);
            dy = fmaxf(dy, 0.0f);
            const float inter = dx * dy;
            const float uni   = area_a + gb.z * gb.w - inter;
            const float iou   = inter * __builtin_amdgcn_rcpf(uni);
            if (iou > best) { best = iou; bi = gg; }   // strict > = first argmax
        }
    }
    s_best[tid] = best;
    s_bi[tid]   = bi;
    __syncthreads();   // drains primes too — they had the whole IoU phase to land

    // ---- combine halves, flags->mask, xywh loss + hot gather (rare lanes) ----
    float lx = 0.0f, pcnt = 0.0f, hot = 0.0f;
    if (tid < APB) {
        const float bhi = s_best[tid + APB];
        if (bhi > best) { best = bhi; bi = s_bi[tid + APB]; }
        const bool pos = best > 0.5f;
        const bool neg = best < 0.4f;
        if (pos) {                                 // rare (~0.4% of anchors)
#pragma clang fp contract(off)
            const int cat = gcat[bi];
            pcnt = 1.0f;
            hot  = cls_logits[((size_t)blk * APB + tid) * NCLS + cat];
            const float4 g = gt4[bi];
            const float4 t = ((const float4*)t_xywh)[(size_t)b * NANCH + n];
            const float tx = (g.x - acx) / aw;
            const float ty = (g.y - acy) / ah;
            const float tw = logf(g.z / aw + 1e-8f);
            const float th = logf(g.w / ah + 1e-8f);
            const float d0 = t.x - tx, d1 = t.y - ty, d2 = t.z - tw, d3 = t.w - th;
            lx = d0 * d0 + d1 * d1 + d2 * d2 + d3 * d3;
        }
        s_mask[tid] = (pos | neg) ? 1.0f : 0.0f;
    }
    __syncthreads();

    // ---- hoist the 10 per-f4 masks into registers (full unroll -> static idx) ----
    float mk[KI];
#pragma unroll
    for (int k = 0; k < KI; ++k)
        mk[k] = s_mask[(k * NTHR + tid) / 20];

    // ---- streaming BCE, explicit 4-deep load pipeline ----
    float l2 = 0.0f;
    COMP(P0, 0)  P0 = base[4 * NTHR + tid];
    COMP(P1, 1)  P1 = base[5 * NTHR + tid];
    COMP(P2, 2)  P2 = base[6 * NTHR + tid];
    COMP(P3, 3)  P3 = base[7 * NTHR + tid];
    COMP(P0, 4)  P0 = base[8 * NTHR + tid];
    COMP(P1, 5)  P1 = base[9 * NTHR + tid];
    COMP(P2, 6)
    COMP(P3, 7)
    COMP(P0, 8)
    COMP(P1, 9)

    // ---- block reduction of (l2, lx, pcnt, hot) ----
    float v0 = l2, v1 = lx, v2 = pcnt, v3 = hot;
    for (int o = 32; o > 0; o >>= 1) {
        v0 += __shfl_down(v0, o);
        v1 += __shfl_down(v1, o);
        v2 += __shfl_down(v2, o);
        v3 += __shfl_down(v3, o);
    }
    const int wave = tid >> 6;
    if ((tid & 63) == 0) {
        s_red[wave * 4 + 0] = v0;
        s_red[wave * 4 + 1] = v1;
        s_red[wave * 4 + 2] = v2;
        s_red[wave * 4 + 3] = v3;
    }
    __syncthreads();
    if (tid == 0) {
        float q0 = 0.0f, q1 = 0.0f, q2 = 0.0f, q3 = 0.0f;
        for (int w2 = 0; w2 < 4; ++w2) {
            q0 += s_red[w2 * 4 + 0];
            q1 += s_red[w2 * 4 + 1];
            q2 += s_red[w2 * 4 + 2];
            q3 += s_red[w2 * 4 + 3];
        }
        part[blk] = make_float4(q0, q1, q2, q3);
    }
}

// ---- fold 2304 block partials into the scalar loss ----
__global__ __launch_bounds__(256) void retina_final(
    const float4* __restrict__ part, float* __restrict__ out)
{
    __shared__ float s_l2[NB], s_pc[NB], s_ht[NB], s_lxr[NB];
    const int tid = threadIdx.x;
    const int img = tid >> 5, l = tid & 31;    // 32 lanes per image

    float l2s = 0.0f, lxs = 0.0f, pcs = 0.0f, hts = 0.0f;
    for (int i = l; i < BLKS_PER_IMG; i += 32) {
        const float4 p = part[img * BLKS_PER_IMG + i];
        l2s += p.x; lxs += p.y; pcs += p.z; hts += p.w;
    }
    for (int o = 16; o > 0; o >>= 1) {         // xor butterfly within the 32-group
        l2s += __shfl_xor(l2s, o);
        lxs += __shfl_xor(lxs, o);
        pcs += __shfl_xor(pcs, o);
        hts += __shfl_xor(hts, o);
    }
    if (l == 0) { s_l2[img] = l2s; s_pc[img] = pcs; s_ht[img] = hts; s_lxr[img] = lxs; }
    __syncthreads();

    if (tid == 0) {
        float s = 0.0f, lxt = 0.0f;
        for (int bb = 0; bb < NB; ++bb) {
            lxt += s_lxr[bb];
            const float lc_b = LN2 * s_l2[bb] - s_ht[bb];
            s += lc_b / (s_pc[bb] + 1.0f);
        }
        out[0] = (lxt + s) / (float)NB;
    }
}

extern "C" void kernel_launch(void* const* d_in, const int* in_sizes, int n_in,
                              void* d_out, int out_size, void* d_ws, size_t ws_size,
                              hipStream_t stream)
{
    const float* t_xywh     = (const float*)d_in[0];
    const float* cls_logits = (const float*)d_in[1];
    const float* gt_bboxes  = (const float*)d_in[2];
    const int*   gt_cats    = (const int*)d_in[3];

    float4* part = (float4*)d_ws;   // 2304 * 16 B = 36.9 KB

    retina_main<<<NBLK, NTHR, 0, stream>>>(t_xywh, cls_logits, gt_bboxes, gt_cats, part);
    retina_final<<<1, 256, 0, stream>>>(part, (float*)d_out);
}